// Round 1
// baseline (347.507 us; speedup 1.0000x reference)
//
#include <hip/hip_runtime.h>
#include <stdint.h>

#define Bb 2
#define Tt 2048
#define Cc 1024
#define Hh 16
#define HD 64
#define C3 3072

typedef __bf16 bf16x8 __attribute__((ext_vector_type(8)));
typedef float  f32x4  __attribute__((ext_vector_type(4)));
typedef unsigned short u16;
typedef u16 u16x8 __attribute__((ext_vector_type(8)));
typedef u16 u16x4 __attribute__((ext_vector_type(4)));

__device__ __forceinline__ u16 f2bf(float f) {
  union { float f; unsigned u; } v; v.f = f;
  return (u16)((v.u + 0x7fffu + ((v.u >> 16) & 1u)) >> 16);  // RNE
}

// async global->LDS, 16B per lane. LDS dest is wave-uniform base + lane*16.
__device__ __forceinline__ void gl2lds16(const void* g, void* s) {
  __builtin_amdgcn_global_load_lds(
      (__attribute__((address_space(1))) void*)(g),
      (__attribute__((address_space(3))) void*)(s), 16, 0, 0);
}

// ---------------- fp32 -> bf16 elementwise ----------------
__global__ void cvt_x_kernel(const float* __restrict__ in, u16* __restrict__ out, int n4) {
  int i = blockIdx.x * blockDim.x + threadIdx.x;
  if (i < n4) {
    float4 v = ((const float4*)in)[i];
    u16x4 o = { f2bf(v.x), f2bf(v.y), f2bf(v.z), f2bf(v.w) };
    ((u16x4*)out)[i] = o;
  }
}

// ---------------- fp32 [R][C] -> bf16 [C][R] tiled transpose ----------------
__global__ void transpose_cvt(const float* __restrict__ in, u16* __restrict__ out,
                              int R, int C) {
  __shared__ u16 tile[64][65];
  int c0 = blockIdx.x * 64, r0 = blockIdx.y * 64;
  int x = threadIdx.x & 63, y = threadIdx.x >> 6;
  #pragma unroll
  for (int rr = y; rr < 64; rr += 4)
    tile[rr][x] = f2bf(in[(size_t)(r0 + rr) * C + c0 + x]);
  __syncthreads();
  #pragma unroll
  for (int rr = y; rr < 64; rr += 4)
    out[(size_t)(c0 + rr) * R + r0 + x] = tile[x][rr];
}

// ---------------- bf16 GEMM: C[M][N] = A[M][K] * Bt[N][K]^T + bias ----------------
// 128x128 block tile, BK=32, 4 waves (2x2), each wave 64x64 = 4x4 MFMA tiles.
template <int OUT_BF16>
__global__ __launch_bounds__(256)
void gemm_bt(const u16* __restrict__ A, const u16* __restrict__ Bt,
             const float* __restrict__ bias, void* __restrict__ Cout,
             int M, int N, int K) {
  __shared__ u16 As[128 * 32];
  __shared__ u16 Bs[128 * 32];
  const int tid = threadIdx.x;
  const int ln  = tid & 63;
  const int w   = tid >> 6;
  const int wm  = w >> 1, wn = w & 1;
  const int l15 = ln & 15, lq = ln >> 4;
  const int m0 = blockIdx.y * 128, n0 = blockIdx.x * 128;

  f32x4 acc[4][4];
  #pragma unroll
  for (int i = 0; i < 4; ++i)
    #pragma unroll
    for (int j = 0; j < 4; ++j)
      acc[i][j] = (f32x4){0.f, 0.f, 0.f, 0.f};

  for (int k0 = 0; k0 < K; k0 += 32) {
    #pragma unroll
    for (int i = 0; i < 2; ++i) {
      int chunk = i * 256 + tid;      // 0..511, 8 bf16 each
      int row = chunk >> 2;           // tile row 0..127
      int cg  = chunk & 3;            // k-group
      gl2lds16(A  + (size_t)(m0 + row) * K + k0 + cg * 8,
               (char*)As + (size_t)(i * 256 + w * 64) * 16);
      gl2lds16(Bt + (size_t)(n0 + row) * K + k0 + cg * 8,
               (char*)Bs + (size_t)(i * 256 + w * 64) * 16);
    }
    __syncthreads();
    bf16x8 af[4], bfr[4];
    #pragma unroll
    for (int i = 0; i < 4; ++i) {
      af[i]  = *(const bf16x8*)&As[(wm * 64 + i * 16 + l15) * 32 + lq * 8];
      bfr[i] = *(const bf16x8*)&Bs[(wn * 64 + i * 16 + l15) * 32 + lq * 8];
    }
    #pragma unroll
    for (int i = 0; i < 4; ++i)
      #pragma unroll
      for (int j = 0; j < 4; ++j)
        acc[i][j] = __builtin_amdgcn_mfma_f32_16x16x32_bf16(af[i], bfr[j], acc[i][j], 0, 0, 0);
    __syncthreads();
  }

  #pragma unroll
  for (int i = 0; i < 4; ++i) {
    int row = m0 + wm * 64 + i * 16 + lq * 4;
    #pragma unroll
    for (int j = 0; j < 4; ++j) {
      int col = n0 + wn * 64 + j * 16 + l15;
      float bsv = bias[col];
      #pragma unroll
      for (int r = 0; r < 4; ++r) {
        float v = acc[i][j][r] + bsv;
        if (OUT_BF16) ((u16*)Cout)[(size_t)(row + r) * N + col] = f2bf(v);
        else          ((float*)Cout)[(size_t)(row + r) * N + col] = v;
      }
    }
  }
}

// ---------------- fused causal flash attention ----------------
// grid = B*H*(T/64); block 256 = 4 waves; wave handles 16 query rows.
__global__ __launch_bounds__(256)
void attn_fused(const u16* __restrict__ qkv, u16* __restrict__ y) {
  __shared__ u16 Ks[64 * 64];        // [kv][d]
  __shared__ u16 Vts[64 * 64];       // [d][kv]
  __shared__ u16 Ps[4][16 * 64];     // per-wave P [m][kv]
  const int tid = threadIdx.x;
  const int ln = tid & 63, w = tid >> 6;
  const int l15 = ln & 15, lq = ln >> 4;
  const int bx = blockIdx.x;
  const int qt = 31 - (bx & 31);     // heavy tiles first
  const int h  = (bx >> 5) & 15;
  const int b  = bx >> 9;
  const int q0 = qt * 64;

  // Q fragments (A-layout): row = q0 + w*16 + l15, k = lq*8 (+32)
  const int qrow = q0 + w * 16 + l15;
  const size_t qbase = (size_t)(b * Tt + qrow) * C3 + h * HD;
  bf16x8 qf0 = *(const bf16x8*)(qkv + qbase + lq * 8);
  bf16x8 qf1 = *(const bf16x8*)(qkv + qbase + 32 + lq * 8);

  f32x4 o[4];
  #pragma unroll
  for (int j = 0; j < 4; ++j) o[j] = (f32x4){0.f, 0.f, 0.f, 0.f};
  float mprev[4] = {-__builtin_inff(), -__builtin_inff(), -__builtin_inff(), -__builtin_inff()};
  float lsum[4]  = {0.f, 0.f, 0.f, 0.f};

  for (int kk = 0; kk <= q0; kk += 64) {
    __syncthreads();   // protect Ks/Vts from previous iteration's readers
    #pragma unroll
    for (int i = 0; i < 2; ++i) {
      int chunk = i * 256 + tid;     // 0..511
      int row = chunk >> 3;          // kv row 0..63
      int cg  = chunk & 7;           // d-group
      size_t rbase = (size_t)(b * Tt + kk + row) * C3 + h * HD + cg * 8;
      gl2lds16(qkv + rbase + Cc, (char*)Ks + (size_t)(i * 256 + w * 64) * 16);
      u16x8 v = *(const u16x8*)(qkv + rbase + 2 * Cc);
      #pragma unroll
      for (int j = 0; j < 8; ++j) Vts[(cg * 8 + j) * 64 + row] = v[j];
    }
    __syncthreads();

    // S = Q K^T  (per wave: 16 x 64)
    f32x4 s[4];
    #pragma unroll
    for (int j = 0; j < 4; ++j) {
      bf16x8 kf0 = *(const bf16x8*)&Ks[(j * 16 + l15) * 64 + lq * 8];
      bf16x8 kf1 = *(const bf16x8*)&Ks[(j * 16 + l15) * 64 + 32 + lq * 8];
      f32x4 z = (f32x4){0.f, 0.f, 0.f, 0.f};
      z = __builtin_amdgcn_mfma_f32_16x16x32_bf16(qf0, kf0, z, 0, 0, 0);
      z = __builtin_amdgcn_mfma_f32_16x16x32_bf16(qf1, kf1, z, 0, 0, 0);
      s[j] = z;
    }

    // mask + scale + online softmax
    #pragma unroll
    for (int r = 0; r < 4; ++r) {
      int rowg = q0 + w * 16 + lq * 4 + r;
      float mx = -__builtin_inff();
      #pragma unroll
      for (int j = 0; j < 4; ++j) {
        int colg = kk + j * 16 + l15;
        float v = s[j][r] * 0.125f;
        v = (colg > rowg) ? -__builtin_inff() : v;
        s[j][r] = v;
        mx = fmaxf(mx, v);
      }
      mx = fmaxf(mx, __shfl_xor(mx, 1));
      mx = fmaxf(mx, __shfl_xor(mx, 2));
      mx = fmaxf(mx, __shfl_xor(mx, 4));
      mx = fmaxf(mx, __shfl_xor(mx, 8));
      float mnew = fmaxf(mprev[r], mx);
      float alpha = __expf(mprev[r] - mnew);
      float psum = 0.f;
      #pragma unroll
      for (int j = 0; j < 4; ++j) {
        float p = __expf(s[j][r] - mnew);
        s[j][r] = p;
        psum += p;
      }
      psum += __shfl_xor(psum, 1);
      psum += __shfl_xor(psum, 2);
      psum += __shfl_xor(psum, 4);
      psum += __shfl_xor(psum, 8);
      lsum[r] = lsum[r] * alpha + psum;
      mprev[r] = mnew;
      #pragma unroll
      for (int jd = 0; jd < 4; ++jd) o[jd][r] *= alpha;
    }

    // P (C-layout) -> LDS -> A-layout
    #pragma unroll
    for (int r = 0; r < 4; ++r)
      #pragma unroll
      for (int j = 0; j < 4; ++j)
        Ps[w][(lq * 4 + r) * 64 + j * 16 + l15] = f2bf(s[j][r]);

    bf16x8 pf0 = *(const bf16x8*)&Ps[w][l15 * 64 + lq * 8];
    bf16x8 pf1 = *(const bf16x8*)&Ps[w][l15 * 64 + 32 + lq * 8];
    #pragma unroll
    for (int jd = 0; jd < 4; ++jd) {
      bf16x8 vf0 = *(const bf16x8*)&Vts[(jd * 16 + l15) * 64 + lq * 8];
      bf16x8 vf1 = *(const bf16x8*)&Vts[(jd * 16 + l15) * 64 + 32 + lq * 8];
      o[jd] = __builtin_amdgcn_mfma_f32_16x16x32_bf16(pf0, vf0, o[jd], 0, 0, 0);
      o[jd] = __builtin_amdgcn_mfma_f32_16x16x32_bf16(pf1, vf1, o[jd], 0, 0, 0);
    }
  }

  #pragma unroll
  for (int r = 0; r < 4; ++r) {
    int rowg = q0 + w * 16 + lq * 4 + r;
    float inv = 1.f / lsum[r];
    #pragma unroll
    for (int jd = 0; jd < 4; ++jd) {
      float v = o[jd][r] * inv;
      y[(size_t)(b * Tt + rowg) * Cc + h * HD + jd * 16 + l15] = f2bf(v);
    }
  }
}

extern "C" void kernel_launch(void* const* d_in, const int* in_sizes, int n_in,
                              void* d_out, int out_size, void* d_ws, size_t ws_size,
                              hipStream_t stream) {
  const float* x      = (const float*)d_in[0];
  const float* w_attn = (const float*)d_in[1];
  const float* b_attn = (const float*)d_in[2];
  const float* w_proj = (const float*)d_in[3];
  const float* b_proj = (const float*)d_in[4];
  float* out = (float*)d_out;

  char* ws = (char*)d_ws;
  u16* xb  = (u16*)(ws + 0);          // 4096x1024 bf16   (8 MB)
  u16* wat = (u16*)(ws + 8388608);    // 3072x1024 bf16   (6 MB)   w_attn^T
  u16* wpt = (u16*)(ws + 14680064);   // 1024x1024 bf16   (2 MB)   w_proj^T
  u16* qkv = (u16*)(ws + 16777216);   // 4096x3072 bf16   (24 MB)
  u16* yb  = (u16*)(ws + 41943040);   // 4096x1024 bf16   (8 MB)

  cvt_x_kernel<<<4096, 256, 0, stream>>>(x, xb, 1048576);
  transpose_cvt<<<dim3(48, 16), 256, 0, stream>>>(w_attn, wat, 1024, 3072);
  transpose_cvt<<<dim3(16, 16), 256, 0, stream>>>(w_proj, wpt, 1024, 1024);
  gemm_bt<1><<<dim3(24, 32), 256, 0, stream>>>(xb, wat, b_attn, (void*)qkv, 4096, 3072, 1024);
  attn_fused<<<1024, 256, 0, stream>>>(qkv, yb);
  gemm_bt<0><<<dim3(8, 32), 256, 0, stream>>>(yb, wpt, b_proj, (void*)out, 4096, 1024, 1024);
}

// Round 2
// 301.806 us; speedup vs baseline: 1.1514x; 1.1514x over previous
//
#include <hip/hip_runtime.h>
#include <stdint.h>

#define Bb 2
#define Tt 2048
#define Cc 1024
#define Hh 16
#define HD 64
#define C3 3072

typedef __bf16 bf16x8 __attribute__((ext_vector_type(8)));
typedef float  f32x4  __attribute__((ext_vector_type(4)));
typedef unsigned short u16;
typedef u16 u16x8 __attribute__((ext_vector_type(8)));
typedef u16 u16x4 __attribute__((ext_vector_type(4)));

#define SCALE2 0.18033688f  /* 1/sqrt(64) * log2(e) */

__device__ __forceinline__ u16 f2bf(float f) {
  union { float f; unsigned u; } v; v.f = f;
  return (u16)((v.u + 0x7fffu + ((v.u >> 16) & 1u)) >> 16);  // RNE
}
__device__ __forceinline__ float bf2f(u16 a) {
  union { unsigned u; float f; } v; v.u = ((unsigned)a) << 16; return v.f;
}

// async global->LDS, 16B per lane. LDS dest is wave-uniform base + lane*16.
__device__ __forceinline__ void gl2lds16(const void* g, void* s) {
  __builtin_amdgcn_global_load_lds(
      (__attribute__((address_space(1))) void*)(g),
      (__attribute__((address_space(3))) void*)(s), 16, 0, 0);
}

// ---------------- fp32 -> bf16 elementwise ----------------
__global__ void cvt_x_kernel(const float* __restrict__ in, u16* __restrict__ out, int n4) {
  int i = blockIdx.x * blockDim.x + threadIdx.x;
  if (i < n4) {
    float4 v = ((const float4*)in)[i];
    u16x4 o = { f2bf(v.x), f2bf(v.y), f2bf(v.z), f2bf(v.w) };
    ((u16x4*)out)[i] = o;
  }
}

// ---------------- fp32 [R][C] -> bf16 [C][R] tiled transpose ----------------
__global__ void transpose_cvt(const float* __restrict__ in, u16* __restrict__ out,
                              int R, int C) {
  __shared__ u16 tile[64][65];
  int c0 = blockIdx.x * 64, r0 = blockIdx.y * 64;
  int x = threadIdx.x & 63, y = threadIdx.x >> 6;
  #pragma unroll
  for (int rr = y; rr < 64; rr += 4)
    tile[rr][x] = f2bf(in[(size_t)(r0 + rr) * C + c0 + x]);
  __syncthreads();
  #pragma unroll
  for (int rr = y; rr < 64; rr += 4)
    out[(size_t)(c0 + rr) * R + r0 + x] = tile[x][rr];
}

// ---------------- bf16 GEMM: C[M][N] = A[M][K] * Bt[N][K]^T + bias ----------------
// 128x128 block tile, BK=32, 4 waves (2x2), each wave 64x64 = 4x4 MFMA tiles.
// MODE 0: fp32 out, ldc=N.   MODE 1: bf16 out with ldc=2048 for cols<2048 (Q,K),
//         V cols (>=2048) redirected transposed into Vt[b][h][d][t].
template <int MODE>
__global__ __launch_bounds__(256)
void gemm_bt(const u16* __restrict__ A, const u16* __restrict__ Bt,
             const float* __restrict__ bias, void* __restrict__ Cout,
             u16* __restrict__ Vt, int M, int N, int K) {
  __shared__ u16 As[128 * 32];
  __shared__ u16 Bs[128 * 32];
  const int tid = threadIdx.x;
  const int ln  = tid & 63;
  const int w   = tid >> 6;
  const int wm  = w >> 1, wn = w & 1;
  const int l15 = ln & 15, lq = ln >> 4;
  const int m0 = blockIdx.y * 128, n0 = blockIdx.x * 128;

  f32x4 acc[4][4];
  #pragma unroll
  for (int i = 0; i < 4; ++i)
    #pragma unroll
    for (int j = 0; j < 4; ++j)
      acc[i][j] = (f32x4){0.f, 0.f, 0.f, 0.f};

  for (int k0 = 0; k0 < K; k0 += 32) {
    #pragma unroll
    for (int i = 0; i < 2; ++i) {
      int chunk = i * 256 + tid;      // 0..511, 8 bf16 each
      int row = chunk >> 2;           // tile row 0..127
      int cg  = chunk & 3;            // k-group
      gl2lds16(A  + (size_t)(m0 + row) * K + k0 + cg * 8,
               (char*)As + (size_t)(i * 256 + w * 64) * 16);
      gl2lds16(Bt + (size_t)(n0 + row) * K + k0 + cg * 8,
               (char*)Bs + (size_t)(i * 256 + w * 64) * 16);
    }
    __syncthreads();
    bf16x8 af[4], bfr[4];
    #pragma unroll
    for (int i = 0; i < 4; ++i) {
      af[i]  = *(const bf16x8*)&As[(wm * 64 + i * 16 + l15) * 32 + lq * 8];
      bfr[i] = *(const bf16x8*)&Bs[(wn * 64 + i * 16 + l15) * 32 + lq * 8];
    }
    #pragma unroll
    for (int i = 0; i < 4; ++i)
      #pragma unroll
      for (int j = 0; j < 4; ++j)
        acc[i][j] = __builtin_amdgcn_mfma_f32_16x16x32_bf16(af[i], bfr[j], acc[i][j], 0, 0, 0);
    __syncthreads();
  }

  if (MODE == 1 && n0 >= 2048) {
    // V block: write transposed into Vt[(b*16+h)*64+d][t] = Vt[b*1024+hd][t]
    #pragma unroll
    for (int i = 0; i < 4; ++i) {
      int rowb = m0 + wm * 64 + i * 16 + lq * 4;   // 4 consecutive t
      int b_ = rowb >> 11, t0 = rowb & 2047;
      #pragma unroll
      for (int j = 0; j < 4; ++j) {
        int col = n0 + wn * 64 + j * 16 + l15;
        int hd = col - 2048;
        float bsv = bias[col];
        u16x4 pk;
        #pragma unroll
        for (int r = 0; r < 4; ++r) pk[r] = f2bf(acc[i][j][r] + bsv);
        *(u16x4*)&Vt[(size_t)(b_ * 1024 + hd) * Tt + t0] = pk;
      }
    }
  } else {
    const int ldc = (MODE == 1) ? 2048 : N;
    #pragma unroll
    for (int i = 0; i < 4; ++i) {
      int row = m0 + wm * 64 + i * 16 + lq * 4;
      #pragma unroll
      for (int j = 0; j < 4; ++j) {
        int col = n0 + wn * 64 + j * 16 + l15;
        float bsv = bias[col];
        #pragma unroll
        for (int r = 0; r < 4; ++r) {
          float v = acc[i][j][r] + bsv;
          if (MODE == 1) ((u16*)Cout)[(size_t)(row + r) * ldc + col] = f2bf(v);
          else           ((float*)Cout)[(size_t)(row + r) * ldc + col] = v;
        }
      }
    }
  }
}

// ---------------- fused causal flash attention ----------------
// grid = B*H*(T/32) = 2048 blocks; block 128 = 2 waves; wave handles 16 query rows.
// qk: [b][t][2048]  (Q cols 0..1023, K cols 1024..2047, per-head 64)
// vt: [b*16+h][d][t] bf16 (V transposed)
__global__ __launch_bounds__(128)
void attn_fused(const u16* __restrict__ qk, const u16* __restrict__ vt,
                u16* __restrict__ y) {
  __shared__ u16 Ks[64 * 64];        // [kv][d]
  __shared__ u16 Vts[64 * 64];       // [d][kv]
  __shared__ u16 Ps[2][16 * 72];     // per-wave P [m][kv], padded stride 72
  const int tid = threadIdx.x;
  const int ln = tid & 63, w = tid >> 6;
  const int l15 = ln & 15, lq = ln >> 4;
  const int bx = blockIdx.x;
  const int qt = 63 - (bx & 63);     // heavy tiles first
  const int h  = (bx >> 6) & 15;
  const int b  = bx >> 10;
  const int q0 = qt * 32;

  // Q fragment (A-layout), prescaled by 1/sqrt(d)*log2(e)
  const int qrow = q0 + w * 16 + l15;
  const size_t qbase = (size_t)(b * Tt + qrow) * 2048 + h * HD;
  u16x8 qr0 = *(const u16x8*)(qk + qbase + lq * 8);
  u16x8 qr1 = *(const u16x8*)(qk + qbase + 32 + lq * 8);
  u16x8 qs0, qs1;
  #pragma unroll
  for (int j = 0; j < 8; ++j) {
    qs0[j] = f2bf(bf2f(qr0[j]) * SCALE2);
    qs1[j] = f2bf(bf2f(qr1[j]) * SCALE2);
  }
  bf16x8 qf0 = __builtin_bit_cast(bf16x8, qs0);
  bf16x8 qf1 = __builtin_bit_cast(bf16x8, qs1);

  const u16* kbase  = qk + (size_t)(b * Tt) * 2048 + 1024 + h * HD;
  const u16* vtbase = vt + (size_t)(b * 1024 + h * HD) * Tt;

  f32x4 o[4];
  #pragma unroll
  for (int j = 0; j < 4; ++j) o[j] = (f32x4){0.f, 0.f, 0.f, 0.f};
  float mprev[4] = {-__builtin_inff(), -__builtin_inff(), -__builtin_inff(), -__builtin_inff()};
  float lsum[4]  = {0.f, 0.f, 0.f, 0.f};

  const int nkv = ((q0 + 31) >> 6) + 1;
  for (int it = 0; it < nkv; ++it) {
    const int kk = it * 64;
    __syncthreads();   // previous iteration's readers done
    #pragma unroll
    for (int i = 0; i < 4; ++i) {
      int chunk = i * 128 + tid;     // 0..511
      int rr = chunk >> 3;           // K: kv row; V: d row
      int cg = chunk & 7;
      gl2lds16(kbase + (size_t)(kk + rr) * 2048 + cg * 8,
               (char*)Ks + (size_t)(i * 128 + w * 64) * 16);
      gl2lds16(vtbase + (size_t)rr * Tt + kk + cg * 8,
               (char*)Vts + (size_t)(i * 128 + w * 64) * 16);
    }
    __syncthreads();

    // S = Q K^T  (per wave: 16 x 64), already in log2 domain
    f32x4 s[4];
    #pragma unroll
    for (int j = 0; j < 4; ++j) {
      bf16x8 kf0 = *(const bf16x8*)&Ks[(j * 16 + l15) * 64 + lq * 8];
      bf16x8 kf1 = *(const bf16x8*)&Ks[(j * 16 + l15) * 64 + 32 + lq * 8];
      f32x4 z = (f32x4){0.f, 0.f, 0.f, 0.f};
      z = __builtin_amdgcn_mfma_f32_16x16x32_bf16(qf0, kf0, z, 0, 0, 0);
      z = __builtin_amdgcn_mfma_f32_16x16x32_bf16(qf1, kf1, z, 0, 0, 0);
      s[j] = z;
    }

    const bool domask = (kk + 64 > q0);

    #pragma unroll
    for (int r = 0; r < 4; ++r) {
      int rowg = q0 + w * 16 + lq * 4 + r;
      if (domask) {
        #pragma unroll
        for (int j = 0; j < 4; ++j) {
          int colg = kk + j * 16 + l15;
          if (colg > rowg) s[j][r] = -__builtin_inff();
        }
      }
      float mx = fmaxf(fmaxf(s[0][r], s[1][r]), fmaxf(s[2][r], s[3][r]));
      mx = fmaxf(mx, __shfl_xor(mx, 1));
      mx = fmaxf(mx, __shfl_xor(mx, 2));
      mx = fmaxf(mx, __shfl_xor(mx, 4));
      mx = fmaxf(mx, __shfl_xor(mx, 8));
      float mnew = fmaxf(mprev[r], mx);
      float alpha = __builtin_amdgcn_exp2f(mprev[r] - mnew);
      float psum = 0.f;
      #pragma unroll
      for (int j = 0; j < 4; ++j) {
        float p = __builtin_amdgcn_exp2f(s[j][r] - mnew);
        s[j][r] = p;
        psum += p;
      }
      psum += __shfl_xor(psum, 1);
      psum += __shfl_xor(psum, 2);
      psum += __shfl_xor(psum, 4);
      psum += __shfl_xor(psum, 8);
      lsum[r] = lsum[r] * alpha + psum;
      mprev[r] = mnew;
      #pragma unroll
      for (int jd = 0; jd < 4; ++jd) o[jd][r] *= alpha;
    }

    // P (C-layout) -> LDS (padded) -> A-layout
    #pragma unroll
    for (int r = 0; r < 4; ++r)
      #pragma unroll
      for (int j = 0; j < 4; ++j)
        Ps[w][(lq * 4 + r) * 72 + j * 16 + l15] = f2bf(s[j][r]);

    bf16x8 pf0 = *(const bf16x8*)&Ps[w][l15 * 72 + lq * 8];
    bf16x8 pf1 = *(const bf16x8*)&Ps[w][l15 * 72 + 32 + lq * 8];
    #pragma unroll
    for (int jd = 0; jd < 4; ++jd) {
      bf16x8 vf0 = *(const bf16x8*)&Vts[(jd * 16 + l15) * 64 + lq * 8];
      bf16x8 vf1 = *(const bf16x8*)&Vts[(jd * 16 + l15) * 64 + 32 + lq * 8];
      o[jd] = __builtin_amdgcn_mfma_f32_16x16x32_bf16(pf0, vf0, o[jd], 0, 0, 0);
      o[jd] = __builtin_amdgcn_mfma_f32_16x16x32_bf16(pf1, vf1, o[jd], 0, 0, 0);
    }
  }

  #pragma unroll
  for (int r = 0; r < 4; ++r) {
    int rowg = q0 + w * 16 + lq * 4 + r;
    float inv = 1.f / lsum[r];
    #pragma unroll
    for (int jd = 0; jd < 4; ++jd) {
      float v = o[jd][r] * inv;
      y[(size_t)(b * Tt + rowg) * Cc + h * HD + jd * 16 + l15] = f2bf(v);
    }
  }
}

extern "C" void kernel_launch(void* const* d_in, const int* in_sizes, int n_in,
                              void* d_out, int out_size, void* d_ws, size_t ws_size,
                              hipStream_t stream) {
  const float* x      = (const float*)d_in[0];
  const float* w_attn = (const float*)d_in[1];
  const float* b_attn = (const float*)d_in[2];
  const float* w_proj = (const float*)d_in[3];
  const float* b_proj = (const float*)d_in[4];
  float* out = (float*)d_out;

  char* ws = (char*)d_ws;
  u16* xb  = (u16*)(ws + 0);          // 4096x1024 bf16   (8 MB)
  u16* wat = (u16*)(ws + 8388608);    // 3072x1024 bf16   (6 MB)   w_attn^T
  u16* wpt = (u16*)(ws + 14680064);   // 1024x1024 bf16   (2 MB)   w_proj^T
  u16* qkb = (u16*)(ws + 16777216);   // 4096x2048 bf16   (16 MB)  Q,K
  u16* vtb = (u16*)(ws + 33554432);   // 2048x2048 bf16   (8 MB)   V^T per (b,h)
  u16* yb  = (u16*)(ws + 41943040);   // 4096x1024 bf16   (8 MB)

  cvt_x_kernel<<<4096, 256, 0, stream>>>(x, xb, 1048576);
  transpose_cvt<<<dim3(48, 16), 256, 0, stream>>>(w_attn, wat, 1024, 3072);
  transpose_cvt<<<dim3(16, 16), 256, 0, stream>>>(w_proj, wpt, 1024, 1024);
  gemm_bt<1><<<dim3(24, 32), 256, 0, stream>>>(xb, wat, b_attn, (void*)qkb, vtb, 4096, 3072, 1024);
  attn_fused<<<2048, 128, 0, stream>>>(qkb, vtb, yb);
  gemm_bt<0><<<dim3(8, 32), 256, 0, stream>>>(yb, wpt, b_proj, (void*)out, nullptr, 4096, 1024, 1024);
}